// Round 5
// baseline (885.232 us; speedup 1.0000x reference)
//
#include <hip/hip_runtime.h>

typedef unsigned short u16;
typedef __attribute__((ext_vector_type(8))) short short8;
typedef __attribute__((ext_vector_type(4))) float f32x4;

#define MFMA_BF16 __builtin_amdgcn_mfma_f32_16x16x32_bf16

__device__ __forceinline__ u16 f2bf(float f){
  unsigned int u = __builtin_bit_cast(unsigned int, f);
  u += 0x7fffu + ((u >> 16) & 1u);
  return (u16)(u >> 16);
}

// async global->LDS 16B: lane i writes lds_base + i*16
__device__ __forceinline__ void gld16(const void* g, void* l){
  __builtin_amdgcn_global_load_lds(
      (const __attribute__((address_space(1))) unsigned int*)g,
      (__attribute__((address_space(3))) unsigned int*)l, 16, 0, 0);
}

// ---------------- batched fp32 transposes of the 4 weights ----------------
__global__ void k_transpose4(const float* __restrict__ s0, float* __restrict__ d0,
                             const float* __restrict__ s1, float* __restrict__ d1,
                             const float* __restrict__ s2, float* __restrict__ d2,
                             const float* __restrict__ s3, float* __restrict__ d3)
{
  __shared__ float tile[32][33];
  int z = blockIdx.z;
  const float* src = z == 0 ? s0 : z == 1 ? s1 : z == 2 ? s2 : s3;
  float* dst       = z == 0 ? d0 : z == 1 ? d1 : z == 2 ? d2 : d3;
  int rows = z == 0 ? 256 : 1024, cols = z == 0 ? 1024 : 256;
  int c0 = blockIdx.x * 32, r0 = blockIdx.y * 32;
  if (c0 >= cols || r0 >= rows) return;
  int tx = threadIdx.x, ty = threadIdx.y;
#pragma unroll
  for (int i = 0; i < 4; ++i){
    int r = ty + i * 8;
    tile[r][tx] = src[(long)(r0 + r) * cols + c0 + tx];
  }
  __syncthreads();
#pragma unroll
  for (int i = 0; i < 4; ++i){
    int r = ty + i * 8;
    dst[(long)(c0 + r) * rows + r0 + tx] = tile[tx][r];
  }
}

// ---------------- NT MFMA GEMM: C[M,N] = scale * A[M,K] * B[N,K]^T ----------------
__global__ __launch_bounds__(256)
void k_gemm_nt(const float* __restrict__ A, const float* __restrict__ B,
               float* __restrict__ Cf, u16* __restrict__ Cb,
               int M, int N, int K, int lda, int ldb, int ldc,
               long sA, long sB, long sC, float scale)
{
  A += (long)blockIdx.z * sA; B += (long)blockIdx.z * sB;
  if (Cf) Cf += (long)blockIdx.z * sC;
  if (Cb) Cb += (long)blockIdx.z * sC;
  const int n0 = blockIdx.x * 64, m0 = blockIdx.y * 64;
  const int tid = threadIdx.x;
  const int wave = tid >> 6, lane = tid & 63, quad = lane >> 4, l16 = lane & 15;
  __shared__ u16 As[64 * 40];
  __shared__ u16 Bs[64 * 40];
  f32x4 acc[4];
#pragma unroll
  for (int n = 0; n < 4; ++n) acc[n] = (f32x4){0.f, 0.f, 0.f, 0.f};

  const int lr = tid >> 2;
  const int lc = (tid & 3) * 8;
  for (int k0 = 0; k0 < K; k0 += 32){
    {
      const float* pa = &A[(long)(m0 + lr) * lda + k0 + lc];
      float4 a0 = *(const float4*)pa;
      float4 a1 = *(const float4*)(pa + 4);
      short8 pk;
      pk[0]=(short)f2bf(a0.x); pk[1]=(short)f2bf(a0.y); pk[2]=(short)f2bf(a0.z); pk[3]=(short)f2bf(a0.w);
      pk[4]=(short)f2bf(a1.x); pk[5]=(short)f2bf(a1.y); pk[6]=(short)f2bf(a1.z); pk[7]=(short)f2bf(a1.w);
      *(short8*)&As[lr * 40 + lc] = pk;
      const float* pb = &B[(long)(n0 + lr) * ldb + k0 + lc];
      float4 b0 = *(const float4*)pb;
      float4 b1 = *(const float4*)(pb + 4);
      short8 qk;
      qk[0]=(short)f2bf(b0.x); qk[1]=(short)f2bf(b0.y); qk[2]=(short)f2bf(b0.z); qk[3]=(short)f2bf(b0.w);
      qk[4]=(short)f2bf(b1.x); qk[5]=(short)f2bf(b1.y); qk[6]=(short)f2bf(b1.z); qk[7]=(short)f2bf(b1.w);
      *(short8*)&Bs[lr * 40 + lc] = qk;
    }
    __syncthreads();
    short8 a = *(const short8*)&As[(wave * 16 + l16) * 40 + quad * 8];
#pragma unroll
    for (int n = 0; n < 4; ++n){
      short8 b = *(const short8*)&Bs[(n * 16 + l16) * 40 + quad * 8];
      acc[n] = MFMA_BF16(a, b, acc[n], 0, 0, 0);
    }
    __syncthreads();
  }
#pragma unroll
  for (int n = 0; n < 4; ++n)
#pragma unroll
    for (int r = 0; r < 4; ++r){
      int row = m0 + wave * 16 + quad * 4 + r;
      int col = n0 + n * 16 + l16;
      float v = acc[n][r] * scale;
      if (Cf) Cf[(long)row * ldc + col] = v;
      if (Cb) Cb[(long)row * ldc + col] = f2bf(v);
    }
}

// ---------------- fused projections ----------------
__global__ __launch_bounds__(256)
void k_proj(const float* __restrict__ x, const float* __restrict__ Wdq,
            const float* __restrict__ Wdkv, u16* __restrict__ xq,
            float* __restrict__ ckv_f, u16* __restrict__ ckv_bf, u16* __restrict__ ckvT)
{
  const bool is_kv = blockIdx.x >= 4;
  const float* B = is_kv ? Wdkv : Wdq;
  const int n0 = (blockIdx.x & 3) * 64, m0 = blockIdx.y * 64;
  const int tid = threadIdx.x;
  const int wave = tid >> 6, lane = tid & 63, quad = lane >> 4, l16 = lane & 15;
  __shared__ u16 As[64 * 40];
  __shared__ u16 Bs[64 * 40];
  f32x4 acc[4];
#pragma unroll
  for (int n = 0; n < 4; ++n) acc[n] = (f32x4){0.f, 0.f, 0.f, 0.f};

  const int lr = tid >> 2;
  const int lc = (tid & 3) * 8;
  for (int k0 = 0; k0 < 1024; k0 += 32){
    {
      const float* pa = &x[(long)(m0 + lr) * 1024 + k0 + lc];
      float4 a0 = *(const float4*)pa;
      float4 a1 = *(const float4*)(pa + 4);
      short8 pk;
      pk[0]=(short)f2bf(a0.x); pk[1]=(short)f2bf(a0.y); pk[2]=(short)f2bf(a0.z); pk[3]=(short)f2bf(a0.w);
      pk[4]=(short)f2bf(a1.x); pk[5]=(short)f2bf(a1.y); pk[6]=(short)f2bf(a1.z); pk[7]=(short)f2bf(a1.w);
      *(short8*)&As[lr * 40 + lc] = pk;
      const float* pb = &B[(long)(n0 + lr) * 1024 + k0 + lc];
      float4 b0 = *(const float4*)pb;
      float4 b1 = *(const float4*)(pb + 4);
      short8 qk;
      qk[0]=(short)f2bf(b0.x); qk[1]=(short)f2bf(b0.y); qk[2]=(short)f2bf(b0.z); qk[3]=(short)f2bf(b0.w);
      qk[4]=(short)f2bf(b1.x); qk[5]=(short)f2bf(b1.y); qk[6]=(short)f2bf(b1.z); qk[7]=(short)f2bf(b1.w);
      *(short8*)&Bs[lr * 40 + lc] = qk;
    }
    __syncthreads();
    short8 a = *(const short8*)&As[(wave * 16 + l16) * 40 + quad * 8];
#pragma unroll
    for (int n = 0; n < 4; ++n){
      short8 b = *(const short8*)&Bs[(n * 16 + l16) * 40 + quad * 8];
      acc[n] = MFMA_BF16(a, b, acc[n], 0, 0, 0);
    }
    __syncthreads();
  }
  if (!is_kv){
#pragma unroll
    for (int n = 0; n < 4; ++n)
#pragma unroll
      for (int r = 0; r < 4; ++r){
        int row = m0 + wave * 16 + quad * 4 + r;
        int col = n0 + n * 16 + l16;
        xq[(long)row * 256 + col] = f2bf(acc[n][r]);
      }
  } else {
    const int b = (m0 >> 11);
    const int t0 = (m0 & 2047) + wave * 16 + quad * 4;
#pragma unroll
    for (int n = 0; n < 4; ++n){
      int col = n0 + n * 16 + l16;
      u16 pk[4];
#pragma unroll
      for (int r = 0; r < 4; ++r){
        int row = m0 + wave * 16 + quad * 4 + r;
        float v = acc[n][r];
        ckv_f [(long)row * 256 + col] = v;
        ckv_bf[(long)row * 256 + col] = f2bf(v);
        pk[r] = f2bf(v);
      }
      *(uint2*)&ckvT[((long)b * 256 + col) * 2048 + t0] = *(uint2*)pk;
    }
  }
}

// ---------------- fused MLA flash attention ----------------
// 512 threads (8 waves x 16 t-rows), block covers 128 q-rows.
// grid (16 qtiles reversed, 16 heads, 4 batch).
__global__ __launch_bounds__(512, 4)
void k_flash(const u16* __restrict__ xq, const u16* __restrict__ Pt,
             const u16* __restrict__ ckv_bf, const u16* __restrict__ ckvT,
             const u16* __restrict__ Vt, float* __restrict__ y)
{
  const int qt = 15 - (int)blockIdx.x, h = blockIdx.y, b = blockIdx.z;
  const int tid = threadIdx.x;
  const int wg = tid >> 6, lane = tid & 63, quad = lane >> 4, l16 = lane & 15;

  __shared__ u16 X0[64 * 256];   // ckv tile (swizzled); head 16KB re-used as P; q_lat/ctx park lo
  __shared__ u16 X1[256 * 64];   // ckvT tile (swizzled); q_lat/ctx park hi

  const int trow = wg * 16 + l16;                 // 0..127
  const long tglob = (long)b * 2048 + (long)qt * 128;
  u16* Xq = (wg < 4) ? X0 : X1;                   // parking region for this wave's rows
  const int rloc = trow & 63;
  const int sw7 = l16 & 7;                        // == trow&7 for this lane's rows

  const u16* ckv_b  = ckv_bf + (long)b * 2048 * 256;
  const u16* ckvT_b = ckvT   + (long)b * 256 * 2048;

  // staging source offsets (u16 elements); this wave stages chunks wg*4+j (1KB each)
  int offA[4], offB[4];
  {
    int l5 = lane >> 5, g32 = lane & 31;
    int l3 = lane >> 3, g8 = lane & 7;
#pragma unroll
    for (int j = 0; j < 4; ++j){
      int c = wg * 4 + j;
      int s = c * 2 + l5;                         // 0..63
      offA[j] = s * 256 + ((g32 ^ (s & 7)) * 8);
      int l = c * 8 + l3;                         // 0..255
      offB[j] = l * 2048 + ((g8 ^ (l & 7)) * 8);
    }
  }

  // ---- phase 0: q_lat^T = Pt[h](A) x xq(B); park in Xq, read back B-frags aS
  short8 aS[8];
  {
    short8 bq[8];
    const u16* xr = xq + (tglob + trow) * 256;
#pragma unroll
    for (int ks = 0; ks < 8; ++ks)
      bq[ks] = *(const short8*)&xr[ks * 32 + quad * 8];
    const u16* pth = Pt + (long)h * 65536;
#pragma unroll
    for (int mb = 0; mb < 16; ++mb){
      f32x4 acc = (f32x4){0.f, 0.f, 0.f, 0.f};
#pragma unroll
      for (int ks = 0; ks < 8; ++ks){
        short8 pa = *(const short8*)&pth[(mb * 16 + l16) * 256 + ks * 32 + quad * 8];
        acc = MFMA_BF16(pa, bq[ks], acc, 0, 0, 0);
      }
      // lane holds q_lat[t = wg*16+l16][l = mb*16+quad*4+r]; intra-wave park
#pragma unroll
      for (int r = 0; r < 4; ++r){
        int l = mb * 16 + quad * 4 + r;
        int cs = (((l >> 3) ^ sw7) << 3) | (l & 7);
        Xq[rloc * 256 + cs] = f2bf(acc[r]);
      }
    }
  }
#pragma unroll
  for (int ks = 0; ks < 8; ++ks){
    int gl = ks * 4 + quad;
    aS[ks] = *(const short8*)&Xq[rloc * 256 + ((gl ^ sw7) << 3)];
  }

  // ---- phase 1: online-softmax KV loop over 64-s tiles
  float m_t = -1e30f, l_t = 0.f;
  f32x4 oacc[16];
#pragma unroll
  for (int n = 0; n < 16; ++n) oacc[n] = (f32x4){0.f, 0.f, 0.f, 0.f};

  const int nst = 2 * qt + 2;
  const int tmin_w = qt * 128 + wg * 16;          // min t in this wave

  for (int st = 0; st < nst; ++st){
    __syncthreads();   // A: previous iter's X0/X1/P reads complete
#pragma unroll
    for (int j = 0; j < 4; ++j)
      gld16(ckv_b + (long)st * 16384 + offA[j], &X0[(wg * 4 + j) * 512]);
#pragma unroll
    for (int j = 0; j < 4; ++j)
      gld16(ckvT_b + st * 64 + offB[j], &X1[(wg * 4 + j) * 512]);
    __syncthreads();   // B: DMA drained; tiles ready

    const bool active = (st * 64 <= tmin_w + 15);
    f32x4 sacc[4];
    if (active){
      // S^T = ckv(A: m=s) x q_lat(B: n=t)
#pragma unroll
      for (int mb = 0; mb < 4; ++mb) sacc[mb] = (f32x4){0.f, 0.f, 0.f, 0.f};
#pragma unroll
      for (int ks = 0; ks < 8; ++ks){
#pragma unroll
        for (int mb = 0; mb < 4; ++mb){
          int gl = ks * 4 + quad;
          short8 a = *(const short8*)&X0[(mb * 16 + l16) * 256 + ((gl ^ (l16 & 7)) << 3)];
          sacc[mb] = MFMA_BF16(a, aS[ks], sacc[mb], 0, 0, 0);
        }
      }
      if ((st + 1) * 64 > tmin_w + 1){  // diagonal: mask s > t
        int t = qt * 128 + trow;
#pragma unroll
        for (int mb = 0; mb < 4; ++mb)
#pragma unroll
          for (int r = 0; r < 4; ++r)
            if (st * 64 + mb * 16 + quad * 4 + r > t) sacc[mb][r] = -1e30f;
      }
      // online softmax (per-lane state for t = trow, replicated across quads)
      float rm = sacc[0][0];
#pragma unroll
      for (int mb = 0; mb < 4; ++mb)
#pragma unroll
        for (int r = 0; r < 4; ++r) rm = fmaxf(rm, sacc[mb][r]);
      rm = fmaxf(rm, __shfl_xor(rm, 16, 64));
      rm = fmaxf(rm, __shfl_xor(rm, 32, 64));
      float mnew = fmaxf(m_t, rm);
      float alpha = __expf(m_t - mnew);
      m_t = mnew;
      float rs = 0.f;
#pragma unroll
      for (int mb = 0; mb < 4; ++mb)
#pragma unroll
        for (int r = 0; r < 4; ++r){
          float pe = __expf(sacc[mb][r] - mnew);
          sacc[mb][r] = pe;          // reuse sacc as P
          rs += pe;
        }
      rs += __shfl_xor(rs, 16, 64);
      rs += __shfl_xor(rs, 32, 64);
      l_t = l_t * alpha + rs;
#pragma unroll
      for (int r2 = 0; r2 < 4; ++r2){
        float ar = __shfl(alpha, quad * 4 + r2, 64);
#pragma unroll
        for (int n = 0; n < 16; ++n) oacc[n][r2] *= ar;
      }
    }
    __syncthreads();   // C: all S-phase X0 reads done; P region (X0 head) reusable

    if (active){
      // write P rows (own t-rows) into X0 head: P[trow][s], stride 64, granule-swizzled
#pragma unroll
      for (int mb = 0; mb < 4; ++mb){
        u16 pk[4];
#pragma unroll
        for (int r = 0; r < 4; ++r) pk[r] = f2bf(sacc[mb][r]);
        int c = mb * 16 + quad * 4;                       // 0..63, 8B-aligned group
        int gr = (c >> 3) ^ sw7;
        *(uint2*)&X0[trow * 64 + gr * 8 + (c & 7)] = *(uint2*)pk;
      }
      // PV: O += P(A: m=t, own rows; intra-wave) x ckvT(B: n=l)
      short8 a0 = *(const short8*)&X0[trow * 64 + ((quad ^ sw7) << 3)];
      short8 a1 = *(const short8*)&X0[trow * 64 + (((4 + quad) ^ sw7) << 3)];
#pragma unroll
      for (int n = 0; n < 16; ++n){
        int lr_ = n * 16 + l16;
        int swl = lr_ & 7;
        short8 b0 = *(const short8*)&X1[lr_ * 64 + ((quad ^ swl) << 3)];
        short8 b1 = *(const short8*)&X1[lr_ * 64 + (((4 + quad) ^ swl) << 3)];
        oacc[n] = MFMA_BF16(a0, b0, oacc[n], 0, 0, 0);
        oacc[n] = MFMA_BF16(a1, b1, oacc[n], 0, 0, 0);
      }
    }
  }

  // ---- finalize: ctx = O / l -> park in Xq, y = ctx @ Vt
  __syncthreads();     // last iter's tile reads done before park overwrites
  {
    float linv = 1.f / l_t;
#pragma unroll
    for (int r = 0; r < 4; ++r){
      float lr_ = __shfl(linv, quad * 4 + r, 64);
#pragma unroll
      for (int n = 0; n < 16; ++n) oacc[n][r] *= lr_;
    }
#pragma unroll
    for (int n = 0; n < 16; ++n)
#pragma unroll
      for (int r = 0; r < 4; ++r){
        int trw = wg * 16 + quad * 4 + r;
        int l = n * 16 + l16;
        int cs = (((l >> 3) ^ (trw & 7)) << 3) | (l & 7);
        Xq[(trw & 63) * 256 + cs] = f2bf(oacc[n][r]);
      }
  }
  {
    const u16* vth = Vt + (long)h * 64 * 256;
    short8 ca[8];
#pragma unroll
    for (int ks = 0; ks < 8; ++ks){
      int gl = ks * 4 + quad;
      ca[ks] = *(const short8*)&Xq[rloc * 256 + ((gl ^ sw7) << 3)];
    }
#pragma unroll
    for (int n = 0; n < 4; ++n){
      f32x4 acc = (f32x4){0.f, 0.f, 0.f, 0.f};
#pragma unroll
      for (int ks = 0; ks < 8; ++ks){
        short8 vb = *(const short8*)&vth[(n * 16 + l16) * 256 + ks * 32 + quad * 8];
        acc = MFMA_BF16(ca[ks], vb, acc, 0, 0, 0);
      }
#pragma unroll
      for (int r = 0; r < 4; ++r)
        y[(tglob + wg * 16 + quad * 4 + r) * 1024 + h * 64 + n * 16 + l16] = acc[r];
    }
  }
}

extern "C" void kernel_launch(void* const* d_in, const int* in_sizes, int n_in,
                              void* d_out, int out_size, void* d_ws, size_t ws_size,
                              hipStream_t stream)
{
  (void)in_sizes; (void)n_in; (void)out_size; (void)ws_size;
  const float* x    = (const float*)d_in[0];
  const float* Wdq  = (const float*)d_in[1];
  const float* Wuq  = (const float*)d_in[2];
  const float* Wdkv = (const float*)d_in[3];
  const float* Wuk  = (const float*)d_in[4];
  const float* Wuv  = (const float*)d_in[5];
  const float* Wo   = (const float*)d_in[6];

  float* y_out   = (float*)d_out;                      // (4,2048,1024) fp32
  float* ckv_out = y_out + (size_t)4 * 2048 * 1024;    // (4,2048,256) fp32

  char* base = (char*)d_ws;
  float* wdqT   = (float*)(base + 0);          // 1 MB, dead after keffT
  float* wuqT   = (float*)(base + 1048576);    // 1 MB, dead after pt
  float* wukT   = (float*)(base + 2097152);    // 1 MB, dead after t1T
  float* wuvT   = (float*)(base + 3145728);    // 1 MB, dead after vt
  u16*   ckvT   = (u16*)  (base + 0);          // 4 MB (4,256,2048) written after weights dead
  float* t1T    = (float*)(base + 4194304);    // 256 KB
  float* keffT  = (float*)(base + 4456448);    // 1 MB
  u16*   pt     = (u16*)  (base + 5505024);    // 2 MB (16,256,256), 1/8 folded
  u16*   vt     = (u16*)  (base + 7602176);    // 512 KB (1024,256)
  u16*   xq     = (u16*)  (base + 8126464);    // 4 MB (8192,256)
  u16*   ckv_bf = (u16*)  (base + 12320768);   // 4 MB (4,2048,256) bf16

  k_transpose4<<<dim3(32, 32, 4), dim3(32, 8), 0, stream>>>(
      Wdq, wdqT, Wuq, wuqT, Wuk, wukT, Wuv, wuvT);

  k_gemm_nt<<<dim3(4, 4, 1), 256, 0, stream>>>(wukT, wuqT, t1T, (u16*)0,
      256, 256, 1024, 1024, 1024, 256, 0, 0, 0, 1.f);
  k_gemm_nt<<<dim3(16, 4, 1), 256, 0, stream>>>(t1T, wdqT, keffT, (u16*)0,
      256, 1024, 256, 256, 256, 1024, 0, 0, 0, 1.f);
  k_gemm_nt<<<dim3(4, 4, 16), 256, 0, stream>>>(keffT, wuqT, (float*)0, pt,
      256, 256, 64, 1024, 1024, 256, 64, 64, 65536, 0.125f);
  k_gemm_nt<<<dim3(4, 16, 1), 256, 0, stream>>>(Wo, wuvT, (float*)0, vt,
      1024, 256, 1024, 1024, 1024, 256, 0, 0, 0, 1.f);

  k_proj<<<dim3(8, 128), 256, 0, stream>>>(x, Wdq, Wdkv, xq, ckv_out, ckv_bf, ckvT);

  k_flash<<<dim3(16, 16, 4), 512, 0, stream>>>(xq, pt, ckv_bf, ckvT, vt, y_out);
}